// Round 5
// baseline (505.206 us; speedup 1.0000x reference)
//
#include <hip/hip_runtime.h>
#include <hip/hip_bf16.h>
#include <hip/hip_cooperative_groups.h>

namespace cg = cooperative_groups;

#define N_NODES 100000
#define N_EDGES 800000
#define CSR_BLOCKS 391   // ceil(100000/256)

typedef __attribute__((ext_vector_type(8))) short short8;
typedef __attribute__((ext_vector_type(4))) float f32x4;
typedef __attribute__((ext_vector_type(2))) unsigned int u32x2;

__device__ __forceinline__ float bf2f(ushort u) {
    union { unsigned i; float f; } x; x.i = ((unsigned)u) << 16; return x.f;
}
__device__ __forceinline__ ushort f2bf(float f) {
    union { float f; unsigned u; } x { f };
    unsigned r = x.u + 0x7FFF + ((x.u >> 16) & 1);   // RNE
    return (ushort)(r >> 16);
}

// ---------------------------------------------------------------------------
// Weight prep (one kernel): blocks 0..383 permute W_qkv rows + bias so the
// GEMM emits rows [q(128) | kv(256)]:
//   q  region: col h*16+d            (lane l=h*8+d2 reads ushorts 2l,2l+1)
//   kv region: lane-interleaved quads [k(2d2) k(2d2+1) v(2d2) v(2d2+1)]
//              at col 128 + l*4 + slot  -> per-edge gather is ONE dwordx2.
// Blocks 384..511 convert W_out to bf16.
// ---------------------------------------------------------------------------
__global__ __launch_bounds__(128) void prep_weights(
    const float* __restrict__ Wq, const float* __restrict__ bq,
    const float* __restrict__ Wo,
    ushort* __restrict__ Wqb, float* __restrict__ bqp, ushort* __restrict__ Wob)
{
    int j = blockIdx.x;
    if (j < 384) {
        int h = j / 48, r = j % 48, p;
        if (r < 16)      p = h * 16 + r;
        else if (r < 32) { int d = r - 16; p = 128 + (h * 8 + (d >> 1)) * 4 + (d & 1); }
        else             { int d = r - 32; p = 128 + (h * 8 + (d >> 1)) * 4 + 2 + (d & 1); }
        Wqb[(size_t)p * 128 + threadIdx.x] = f2bf(Wq[(size_t)j * 128 + threadIdx.x]);
        if (threadIdx.x == 0) bqp[p] = bq[j];
    } else {
        int j2 = j - 384;
        Wob[(size_t)j2 * 128 + threadIdx.x] = f2bf(Wo[(size_t)j2 * 128 + threadIdx.x]);
    }
}

// ---------------------------------------------------------------------------
// MFMA GEMM: C[M x Ncols] = A(M x 128) @ B(bf16 Ncols x 128)^T + bias.
// A fp32 (A_F32=1, converted during staging) or bf16. Tile 128x128, 4 waves,
// 4x4 frags of mfma_f32_16x16x32_bf16, BK=64, LDS pad 72.
// SWAPPED operands: mfma(b_frag, a_frag) -> D lane map transposes to
//   our-row = lane&15 (+tiles), our-col = (lane>>4)*4 + reg (+tiles),
// so each lane holds 4 CONSECUTIVE cols per frag -> packed 8B/16B stores.
// (A and B operand lane patterns are identical, so frag loads are unchanged.)
// ---------------------------------------------------------------------------
template<int A_F32, int OUT_BF16>
__global__ __launch_bounds__(256) void gemm_mfma(
    const void* __restrict__ Av, const ushort* __restrict__ B,
    const float* __restrict__ bias, void* __restrict__ Cv,
    int M, int ldc)
{
    __shared__ ushort As[128][72];
    __shared__ ushort Bs[128][72];
    const int t = threadIdx.x;
    const int lane = t & 63;
    const int w = t >> 6;
    const int wm = w >> 1, wn = w & 1;
    const int n0 = blockIdx.x * 128;
    const int j0 = blockIdx.y * 128;

    f32x4 acc[4][4];
    #pragma unroll
    for (int i = 0; i < 4; ++i)
        #pragma unroll
        for (int j = 0; j < 4; ++j) acc[i][j] = (f32x4){0.f, 0.f, 0.f, 0.f};

    for (int kb = 0; kb < 128; kb += 64) {
        #pragma unroll
        for (int it = 0; it < 4; ++it) {
            int c = it * 256 + t;
            int row = c >> 3, g = c & 7;
            int ar = n0 + row; if (ar >= M) ar = M - 1;   // stores guarded
            if (A_F32) {
                const float* ap = (const float*)Av + (size_t)ar * 128 + kb + g * 8;
                float4 a0 = *reinterpret_cast<const float4*>(ap);
                float4 a1 = *reinterpret_cast<const float4*>(ap + 4);
                short8 o;
                o[0] = (short)f2bf(a0.x); o[1] = (short)f2bf(a0.y);
                o[2] = (short)f2bf(a0.z); o[3] = (short)f2bf(a0.w);
                o[4] = (short)f2bf(a1.x); o[5] = (short)f2bf(a1.y);
                o[6] = (short)f2bf(a1.z); o[7] = (short)f2bf(a1.w);
                *reinterpret_cast<short8*>(&As[row][g * 8]) = o;
            } else {
                *reinterpret_cast<short8*>(&As[row][g * 8]) =
                    *reinterpret_cast<const short8*>(
                        (const ushort*)Av + (size_t)ar * 128 + kb + g * 8);
            }
            *reinterpret_cast<short8*>(&Bs[row][g * 8]) =
                *reinterpret_cast<const short8*>(B + (size_t)(j0 + row) * 128 + kb + g * 8);
        }
        __syncthreads();
        #pragma unroll
        for (int kf = 0; kf < 2; ++kf) {
            short8 af[4], bfr[4];
            #pragma unroll
            for (int mf = 0; mf < 4; ++mf)
                af[mf] = *reinterpret_cast<const short8*>(
                    &As[wm * 64 + mf * 16 + (lane & 15)][kf * 32 + (lane >> 4) * 8]);
            #pragma unroll
            for (int nf = 0; nf < 4; ++nf)
                bfr[nf] = *reinterpret_cast<const short8*>(
                    &Bs[wn * 64 + nf * 16 + (lane & 15)][kf * 32 + (lane >> 4) * 8]);
            #pragma unroll
            for (int mf = 0; mf < 4; ++mf)
                #pragma unroll
                for (int nf = 0; nf < 4; ++nf)
                    acc[mf][nf] = __builtin_amdgcn_mfma_f32_16x16x32_bf16(
                        bfr[nf], af[mf], acc[mf][nf], 0, 0, 0);   // SWAPPED
        }
        __syncthreads();
    }

    const int r = lane & 15, c4 = (lane >> 4) * 4;
    #pragma unroll
    for (int mf = 0; mf < 4; ++mf) {
        int row = n0 + wm * 64 + mf * 16 + r;
        if (row >= M) continue;
        #pragma unroll
        for (int nf = 0; nf < 4; ++nf) {
            int col = j0 + wn * 64 + nf * 16 + c4;
            f32x4 a = acc[mf][nf];
            float v0 = a[0] + bias[col],     v1 = a[1] + bias[col + 1];
            float v2 = a[2] + bias[col + 2], v3 = a[3] + bias[col + 3];
            if (OUT_BF16) {
                u32x2 u;
                u[0] = (unsigned)f2bf(v0) | ((unsigned)f2bf(v1) << 16);
                u[1] = (unsigned)f2bf(v2) | ((unsigned)f2bf(v3) << 16);
                *reinterpret_cast<u32x2*>((ushort*)Cv + (size_t)row * ldc + col) = u;
            } else {
                float4 o = {v0, v1, v2, v3};
                *reinterpret_cast<float4*>((float*)Cv + (size_t)row * ldc + col) = o;
            }
        }
    }
}

// ---------------------------------------------------------------------------
// Cooperative CSR build (replaces count/scan1/scan2/scan3/fill):
//  P1 histogram -> P2 per-block scan -> P3 block-0 wave scan of block sums
//  -> P4 add offsets (+sentinel) -> P5 fill. grid.sync() between phases.
//  391 blocks x 256 thr: trivially co-resident. counts/fillc pre-zeroed.
// ---------------------------------------------------------------------------
__global__ __launch_bounds__(256) void build_csr(
    const int* __restrict__ src, const int* __restrict__ dst,
    int* __restrict__ counts, int* __restrict__ fillc,
    int* __restrict__ row_start, int* __restrict__ bsums,
    int* __restrict__ boffs, int* __restrict__ csr_src)
{
    cg::grid_group grid = cg::this_grid();
    const int t = threadIdx.x, b = blockIdx.x;
    const int gid = b * 256 + t;
    const int gsz = CSR_BLOCKS * 256;

    // P1: histogram of dst
    for (int e = gid; e < N_EDGES; e += gsz)
        atomicAdd(&counts[dst[e]], 1);
    grid.sync();

    // P2: block-local exclusive scan of 256 counts
    __shared__ int sd[256];
    int v = (gid < N_NODES) ? counts[gid] : 0;
    sd[t] = v; __syncthreads();
    #pragma unroll
    for (int off = 1; off < 256; off <<= 1) {
        int x = (t >= off) ? sd[t - off] : 0;
        __syncthreads();
        sd[t] += x;
        __syncthreads();
    }
    if (gid < N_NODES) row_start[gid] = sd[t] - v;
    if (t == 255) bsums[b] = sd[255];
    grid.sync();

    // P3: block 0, one wave: exclusive scan of 391 block sums
    if (b == 0 && t < 64) {
        int carry = 0;
        for (int c = 0; c < CSR_BLOCKS; c += 64) {
            int idx = c + t;
            int orig = (idx < CSR_BLOCKS) ? bsums[idx] : 0;
            int val = orig;
            #pragma unroll
            for (int off = 1; off < 64; off <<= 1) {
                int y = __shfl_up(val, off);
                if (t >= off) val += y;
            }
            if (idx < CSR_BLOCKS) boffs[idx] = carry + val - orig;
            carry += __shfl(val, 63);
        }
    }
    grid.sync();

    // P4: add block offsets; sentinel
    if (gid < N_NODES) row_start[gid] += boffs[b];
    if (gid == 0) row_start[N_NODES] = N_EDGES;
    grid.sync();

    // P5: fill csr_src
    for (int e = gid; e < N_EDGES; e += gsz) {
        int d = dst[e];
        int pos = row_start[d] + atomicAdd(&fillc[d], 1);
        csr_src[pos] = src[e];
    }
}

// ---------------------------------------------------------------------------
// Fused attention: one wave per dst node. lane l=h*8+d2 owns channels
// (h, 2d2, 2d2+1). q at node*384 + 2l (ushorts). Per edge: ONE dwordx2 at
// s*384 + 128 + 4l (ushorts) = [k0 k1 v0 v1]. 8-lane shfl_xor score reduce,
// online p-weighted accumulate. Unroll x8 for load-level parallelism.
// Softmax max-shift skipped (|s| bounded, shift-invariant). No atomics.
// ---------------------------------------------------------------------------
__global__ __launch_bounds__(256) void fused_attn(
    const ushort* __restrict__ qkvp, const int* __restrict__ row_start,
    const int* __restrict__ csr_src, ushort* __restrict__ attnb)
{
    int node = (blockIdx.x * 256 + threadIdx.x) >> 6;
    if (node >= N_NODES) return;
    int lane = threadIdx.x & 63;

    unsigned qb = *reinterpret_cast<const unsigned*>(
        qkvp + (size_t)node * 384 + lane * 2);
    float q0 = bf2f((ushort)qb), q1 = bf2f((ushort)(qb >> 16));

    int beg = row_start[node], end = row_start[node + 1];
    float denom = 0.f, a0 = 0.f, a1 = 0.f;
    const ushort* kvbase = qkvp + 128 + lane * 4;

#define GATHER(s, u) u = *reinterpret_cast<const u32x2*>(kvbase + (size_t)(s) * 384);
#define EDGE(u) { \
        float ps = bf2f((ushort)u[0]) * q0 + bf2f((ushort)(u[0] >> 16)) * q1; \
        ps += __shfl_xor(ps, 1); \
        ps += __shfl_xor(ps, 2); \
        ps += __shfl_xor(ps, 4); \
        float p = __expf(ps * 0.25f); \
        denom += p; \
        a0 += p * bf2f((ushort)u[1]); \
        a1 += p * bf2f((ushort)(u[1] >> 16)); }

    int i = beg;
    for (; i + 8 <= end; i += 8) {
        int s0 = csr_src[i],     s1 = csr_src[i + 1];
        int s2 = csr_src[i + 2], s3 = csr_src[i + 3];
        int s4 = csr_src[i + 4], s5 = csr_src[i + 5];
        int s6 = csr_src[i + 6], s7 = csr_src[i + 7];
        u32x2 u0, u1, u2, u3, u4, u5, u6, u7;
        GATHER(s0, u0); GATHER(s1, u1); GATHER(s2, u2); GATHER(s3, u3);
        GATHER(s4, u4); GATHER(s5, u5); GATHER(s6, u6); GATHER(s7, u7);
        EDGE(u0); EDGE(u1); EDGE(u2); EDGE(u3);
        EDGE(u4); EDGE(u5); EDGE(u6); EDGE(u7);
    }
    for (; i < end; ++i) {
        int s = csr_src[i];
        u32x2 u;
        GATHER(s, u);
        EDGE(u);
    }
#undef GATHER
#undef EDGE

    float inv = (end > beg) ? 1.f / denom : 0.f;   // deg-0 node -> zeros
    unsigned o = ((unsigned)f2bf(a1 * inv) << 16) | (unsigned)f2bf(a0 * inv);
    *reinterpret_cast<unsigned*>(attnb + (size_t)node * 128 + lane * 2) = o;
}

// ---------------------------------------------------------------------------
// Workspace (bytes, 16B-aligned), total ~107 MB (ws >= 233 MB per R1):
//   qkvp     [0,           76,800,000)   100000*384 bf16  [q | kv-interleaved]
//   attnb    [76,800,000, 102,400,000)   100000*128 bf16
//   Wqb      [102,400,000,102,498,304)   384*128 bf16 (permuted)
//   Wob      [102,498,304,102,531,072)   128*128 bf16
//   bqp      [102,531,072,102,532,608)   384 f32 (permuted)
//   counts   [102,532,608,102,932,608)   \ zeroed by one memset
//   fillc    [102,932,608,103,332,608)   /
//   rows     [103,332,608,103,732,624)   N+1 ints
//   bsums    [103,732,624,103,734,224)   391 ints (padded)
//   boffs    [103,734,224,103,735,824)   391 ints (padded)
//   csr_src  [103,735,824,106,935,824)
// ---------------------------------------------------------------------------
extern "C" void kernel_launch(void* const* d_in, const int* in_sizes, int n_in,
                              void* d_out, int out_size, void* d_ws, size_t ws_size,
                              hipStream_t stream) {
    const float* x     = (const float*)d_in[0];
    const float* W_qkv = (const float*)d_in[1];
    const float* b_qkv = (const float*)d_in[2];
    const float* W_out = (const float*)d_in[3];
    const float* b_out = (const float*)d_in[4];
    const int*   src   = (const int*)d_in[5];
    const int*   dst   = (const int*)d_in[6];
    float* out = (float*)d_out;

    char* w = (char*)d_ws;
    ushort* qkvp     = (ushort*)(w);
    ushort* attnb    = (ushort*)(w + 76800000);
    ushort* Wqb      = (ushort*)(w + 102400000);
    ushort* Wob      = (ushort*)(w + 102498304);
    float*  bqp      = (float*)(w + 102531072);
    int*    counts   = (int*)(w + 102532608);
    int*    fillc    = (int*)(w + 102932608);
    int*    row_start= (int*)(w + 103332608);
    int*    bsums    = (int*)(w + 103732624);
    int*    boffs    = (int*)(w + 103734224);
    int*    csr_src  = (int*)(w + 103735824);

    hipMemsetAsync(counts, 0, 800000, stream);   // counts + fillc together

    prep_weights<<<512, 128, 0, stream>>>(W_qkv, b_qkv, W_out, Wqb, bqp, Wob);

    gemm_mfma<1, 1><<<dim3(782, 3), 256, 0, stream>>>(
        (const void*)x, Wqb, bqp, (void*)qkvp, N_NODES, 384);

    {
        void* args[] = {(void*)&src, (void*)&dst, (void*)&counts, (void*)&fillc,
                        (void*)&row_start, (void*)&bsums, (void*)&boffs,
                        (void*)&csr_src};
        hipLaunchCooperativeKernel((const void*)build_csr, dim3(CSR_BLOCKS),
                                   dim3(256), args, 0, stream);
    }

    fused_attn<<<25000, 256, 0, stream>>>(qkvp, row_start, csr_src, attnb);

    gemm_mfma<0, 0><<<dim3(782, 1), 256, 0, stream>>>(
        (const void*)attnb, Wob, b_out, (void*)out, N_NODES, 128);
}

// Round 6
// 317.637 us; speedup vs baseline: 1.5905x; 1.5905x over previous
//
#include <hip/hip_runtime.h>
#include <hip/hip_bf16.h>

#define N_NODES 100000
#define N_EDGES 800000
#define NB1 98   // ceil(100000/1024)

typedef __attribute__((ext_vector_type(8))) short short8;
typedef __attribute__((ext_vector_type(4))) float f32x4;
typedef __attribute__((ext_vector_type(2))) unsigned int u32x2;

__device__ __forceinline__ float bf2f(ushort u) {
    union { unsigned i; float f; } x; x.i = ((unsigned)u) << 16; return x.f;
}
__device__ __forceinline__ ushort f2bf(float f) {
    union { float f; unsigned u; } x { f };
    unsigned r = x.u + 0x7FFF + ((x.u >> 16) & 1);   // RNE
    return (ushort)(r >> 16);
}

// ---------------------------------------------------------------------------
// Prep + histogram (one launch, independent work):
//   blocks 0..383: permute W_qkv rows + bias -> [q(128) | kv-interleaved(256)]
//     q  region: col h*16+d (lane l=h*8+d2 reads ushorts 2l,2l+1)
//     kv region: quads [k(2d2) k(2d2+1) v(2d2) v(2d2+1)] at col 128+l*4+slot
//   blocks 384..511: W_out -> bf16
//   blocks 512..6761: histogram of dst into counts
// ---------------------------------------------------------------------------
__global__ __launch_bounds__(128) void prep_and_count(
    const float* __restrict__ Wq, const float* __restrict__ bq,
    const float* __restrict__ Wo, const int* __restrict__ dst,
    ushort* __restrict__ Wqb, float* __restrict__ bqp, ushort* __restrict__ Wob,
    int* __restrict__ counts)
{
    int j = blockIdx.x;
    if (j < 384) {
        int h = j / 48, r = j % 48, p;
        if (r < 16)      p = h * 16 + r;
        else if (r < 32) { int d = r - 16; p = 128 + (h * 8 + (d >> 1)) * 4 + (d & 1); }
        else             { int d = r - 32; p = 128 + (h * 8 + (d >> 1)) * 4 + 2 + (d & 1); }
        Wqb[(size_t)p * 128 + threadIdx.x] = f2bf(Wq[(size_t)j * 128 + threadIdx.x]);
        if (threadIdx.x == 0) bqp[p] = bq[j];
    } else if (j < 512) {
        int j2 = j - 384;
        Wob[(size_t)j2 * 128 + threadIdx.x] = f2bf(Wo[(size_t)j2 * 128 + threadIdx.x]);
    } else {
        int e = (j - 512) * 128 + threadIdx.x;
        if (e < N_EDGES) atomicAdd(&counts[dst[e]], 1);
    }
}

// ---------------------------------------------------------------------------
// MFMA GEMM: C[M x Ncols] = A(M x 128) @ B(bf16 Ncols x 128)^T + bias.
// A fp32 (A_F32=1, converted during staging) or bf16. Tile 128x128, 4 waves,
// 4x4 frags of mfma_f32_16x16x32_bf16, BK=64, LDS pad 72.
// Grid: x = COLUMN block (fast-varying), y = row block, so the (Ncols/128)
// blocks sharing one A row-tile are dispatch-adjacent -> A HBM-fetched once,
// repeats hit L2/L3.
// SWAPPED operands: mfma(b_frag, a_frag) -> each lane holds 4 consecutive
// cols per frag -> packed 8B/16B stores. (A/B operand lane patterns are
// identical, so frag loads are unchanged.)
// ---------------------------------------------------------------------------
template<int A_F32, int OUT_BF16>
__global__ __launch_bounds__(256) void gemm_mfma(
    const void* __restrict__ Av, const ushort* __restrict__ B,
    const float* __restrict__ bias, void* __restrict__ Cv,
    int M, int ldc)
{
    __shared__ ushort As[128][72];
    __shared__ ushort Bs[128][72];
    const int t = threadIdx.x;
    const int lane = t & 63;
    const int w = t >> 6;
    const int wm = w >> 1, wn = w & 1;
    const int n0 = blockIdx.y * 128;   // rows (slow)
    const int j0 = blockIdx.x * 128;   // cols (fast)

    f32x4 acc[4][4];
    #pragma unroll
    for (int i = 0; i < 4; ++i)
        #pragma unroll
        for (int j = 0; j < 4; ++j) acc[i][j] = (f32x4){0.f, 0.f, 0.f, 0.f};

    for (int kb = 0; kb < 128; kb += 64) {
        #pragma unroll
        for (int it = 0; it < 4; ++it) {
            int c = it * 256 + t;
            int row = c >> 3, g = c & 7;
            int ar = n0 + row; if (ar >= M) ar = M - 1;   // stores guarded
            if (A_F32) {
                const float* ap = (const float*)Av + (size_t)ar * 128 + kb + g * 8;
                float4 a0 = *reinterpret_cast<const float4*>(ap);
                float4 a1 = *reinterpret_cast<const float4*>(ap + 4);
                short8 o;
                o[0] = (short)f2bf(a0.x); o[1] = (short)f2bf(a0.y);
                o[2] = (short)f2bf(a0.z); o[3] = (short)f2bf(a0.w);
                o[4] = (short)f2bf(a1.x); o[5] = (short)f2bf(a1.y);
                o[6] = (short)f2bf(a1.z); o[7] = (short)f2bf(a1.w);
                *reinterpret_cast<short8*>(&As[row][g * 8]) = o;
            } else {
                *reinterpret_cast<short8*>(&As[row][g * 8]) =
                    *reinterpret_cast<const short8*>(
                        (const ushort*)Av + (size_t)ar * 128 + kb + g * 8);
            }
            *reinterpret_cast<short8*>(&Bs[row][g * 8]) =
                *reinterpret_cast<const short8*>(B + (size_t)(j0 + row) * 128 + kb + g * 8);
        }
        __syncthreads();
        #pragma unroll
        for (int kf = 0; kf < 2; ++kf) {
            short8 af[4], bfr[4];
            #pragma unroll
            for (int mf = 0; mf < 4; ++mf)
                af[mf] = *reinterpret_cast<const short8*>(
                    &As[wm * 64 + mf * 16 + (lane & 15)][kf * 32 + (lane >> 4) * 8]);
            #pragma unroll
            for (int nf = 0; nf < 4; ++nf)
                bfr[nf] = *reinterpret_cast<const short8*>(
                    &Bs[wn * 64 + nf * 16 + (lane & 15)][kf * 32 + (lane >> 4) * 8]);
            #pragma unroll
            for (int mf = 0; mf < 4; ++mf)
                #pragma unroll
                for (int nf = 0; nf < 4; ++nf)
                    acc[mf][nf] = __builtin_amdgcn_mfma_f32_16x16x32_bf16(
                        bfr[nf], af[mf], acc[mf][nf], 0, 0, 0);   // SWAPPED
        }
        __syncthreads();
    }

    const int r = lane & 15, c4 = (lane >> 4) * 4;
    #pragma unroll
    for (int mf = 0; mf < 4; ++mf) {
        int row = n0 + wm * 64 + mf * 16 + r;
        if (row >= M) continue;
        #pragma unroll
        for (int nf = 0; nf < 4; ++nf) {
            int col = j0 + wn * 64 + nf * 16 + c4;
            f32x4 a = acc[mf][nf];
            float v0 = a[0] + bias[col],     v1 = a[1] + bias[col + 1];
            float v2 = a[2] + bias[col + 2], v3 = a[3] + bias[col + 3];
            if (OUT_BF16) {
                u32x2 u;
                u[0] = (unsigned)f2bf(v0) | ((unsigned)f2bf(v1) << 16);
                u[1] = (unsigned)f2bf(v2) | ((unsigned)f2bf(v3) << 16);
                *reinterpret_cast<u32x2*>((ushort*)Cv + (size_t)row * ldc + col) = u;
            } else {
                float4 o = {v0, v1, v2, v3};
                *reinterpret_cast<float4*>((float*)Cv + (size_t)row * ldc + col) = o;
            }
        }
    }
}

// ---------------------------------------------------------------------------
// CSR build: (histogram in prep_and_count) -> block scan -> global scan ->
// add -> fill.  5-kernel chain (measured ~58us total; cooperative version
// regressed to 250us in R5 — grid.sync is very expensive on 8-XCD).
// ---------------------------------------------------------------------------
__global__ __launch_bounds__(1024) void scan1(
    const int* __restrict__ counts, int* __restrict__ row_start,
    int* __restrict__ bsums)
{
    __shared__ int sd[1024];
    int t = threadIdx.x, i = blockIdx.x * 1024 + t;
    int v = (i < N_NODES) ? counts[i] : 0;
    sd[t] = v; __syncthreads();
    for (int off = 1; off < 1024; off <<= 1) {
        int x = (t >= off) ? sd[t - off] : 0;
        __syncthreads();
        sd[t] += x;
        __syncthreads();
    }
    if (i < N_NODES) row_start[i] = sd[t] - v;   // exclusive within block
    if (t == 1023) bsums[blockIdx.x] = sd[1023];
}

__global__ __launch_bounds__(128) void scan2(
    const int* __restrict__ bsums, int* __restrict__ boffs)
{
    __shared__ int sd[128];
    int t = threadIdx.x;
    int v = (t < NB1) ? bsums[t] : 0;
    sd[t] = v; __syncthreads();
    for (int off = 1; off < 128; off <<= 1) {
        int x = (t >= off) ? sd[t - off] : 0;
        __syncthreads();
        sd[t] += x;
        __syncthreads();
    }
    if (t < NB1) boffs[t] = sd[t] - v;
}

__global__ __launch_bounds__(256) void scan3(
    int* __restrict__ row_start, const int* __restrict__ boffs)
{
    int i = blockIdx.x * 256 + threadIdx.x;
    if (i < N_NODES) row_start[i] += boffs[i >> 10];
    if (i == 0) row_start[N_NODES] = N_EDGES;
}

__global__ __launch_bounds__(256) void fill_csr(
    const int* __restrict__ src, const int* __restrict__ dst,
    const int* __restrict__ row_start, int* __restrict__ fillc,
    int* __restrict__ csr_src)
{
    int e = blockIdx.x * 256 + threadIdx.x;
    if (e >= N_EDGES) return;
    int d = dst[e];
    int pos = row_start[d] + atomicAdd(&fillc[d], 1);
    csr_src[pos] = src[e];
}

// ---------------------------------------------------------------------------
// Fused attention: one wave per dst node. lane l=h*8+d2 owns channels
// (h, 2d2, 2d2+1). q at node*384 + 2l (ushorts). Per edge: ONE dwordx2 at
// s*384 + 128 + 4l (ushorts) = [k0 k1 v0 v1]. 8-lane shfl_xor score reduce,
// online p-weighted accumulate. Unroll x8 for load-level parallelism.
// Softmax max-shift skipped (|s| bounded, shift-invariant). No atomics.
// ---------------------------------------------------------------------------
__global__ __launch_bounds__(256) void fused_attn(
    const ushort* __restrict__ qkvp, const int* __restrict__ row_start,
    const int* __restrict__ csr_src, ushort* __restrict__ attnb)
{
    int node = (blockIdx.x * 256 + threadIdx.x) >> 6;
    if (node >= N_NODES) return;
    int lane = threadIdx.x & 63;

    unsigned qb = *reinterpret_cast<const unsigned*>(
        qkvp + (size_t)node * 384 + lane * 2);
    float q0 = bf2f((ushort)qb), q1 = bf2f((ushort)(qb >> 16));

    int beg = row_start[node], end = row_start[node + 1];
    float denom = 0.f, a0 = 0.f, a1 = 0.f;
    const ushort* kvbase = qkvp + 128 + lane * 4;

#define GATHER(s, u) u = *reinterpret_cast<const u32x2*>(kvbase + (size_t)(s) * 384);
#define EDGE(u) { \
        float ps = bf2f((ushort)u[0]) * q0 + bf2f((ushort)(u[0] >> 16)) * q1; \
        ps += __shfl_xor(ps, 1); \
        ps += __shfl_xor(ps, 2); \
        ps += __shfl_xor(ps, 4); \
        float p = __expf(ps * 0.25f); \
        denom += p; \
        a0 += p * bf2f((ushort)u[1]); \
        a1 += p * bf2f((ushort)(u[1] >> 16)); }

    int i = beg;
    for (; i + 8 <= end; i += 8) {
        int s0 = csr_src[i],     s1 = csr_src[i + 1];
        int s2 = csr_src[i + 2], s3 = csr_src[i + 3];
        int s4 = csr_src[i + 4], s5 = csr_src[i + 5];
        int s6 = csr_src[i + 6], s7 = csr_src[i + 7];
        u32x2 u0, u1, u2, u3, u4, u5, u6, u7;
        GATHER(s0, u0); GATHER(s1, u1); GATHER(s2, u2); GATHER(s3, u3);
        GATHER(s4, u4); GATHER(s5, u5); GATHER(s6, u6); GATHER(s7, u7);
        EDGE(u0); EDGE(u1); EDGE(u2); EDGE(u3);
        EDGE(u4); EDGE(u5); EDGE(u6); EDGE(u7);
    }
    for (; i < end; ++i) {
        int s = csr_src[i];
        u32x2 u;
        GATHER(s, u);
        EDGE(u);
    }
#undef GATHER
#undef EDGE

    float inv = (end > beg) ? 1.f / denom : 0.f;   // deg-0 node -> zeros
    unsigned o = ((unsigned)f2bf(a1 * inv) << 16) | (unsigned)f2bf(a0 * inv);
    *reinterpret_cast<unsigned*>(attnb + (size_t)node * 128 + lane * 2) = o;
}

// ---------------------------------------------------------------------------
// Workspace (bytes, 16B-aligned), total ~107 MB:
//   qkvp     [0,           76,800,000)   100000*384 bf16  [q | kv-interleaved]
//   attnb    [76,800,000, 102,400,000)   100000*128 bf16
//   Wqb      [102,400,000,102,498,304)   384*128 bf16 (permuted)
//   Wob      [102,498,304,102,531,072)   128*128 bf16
//   bqp      [102,531,072,102,532,608)   384 f32 (permuted)
//   counts   [102,532,608,102,932,608)   \ zeroed by one memset
//   fillc    [102,932,608,103,332,608)   /
//   rows     [103,332,608,103,732,624)   N+1 ints
//   bsums    [103,732,624,103,733,136)   98 ints (padded)
//   boffs    [103,733,136,103,733,648)   98 ints (padded)
//   csr_src  [103,733,648,106,933,648)
// ---------------------------------------------------------------------------
extern "C" void kernel_launch(void* const* d_in, const int* in_sizes, int n_in,
                              void* d_out, int out_size, void* d_ws, size_t ws_size,
                              hipStream_t stream) {
    const float* x     = (const float*)d_in[0];
    const float* W_qkv = (const float*)d_in[1];
    const float* b_qkv = (const float*)d_in[2];
    const float* W_out = (const float*)d_in[3];
    const float* b_out = (const float*)d_in[4];
    const int*   src   = (const int*)d_in[5];
    const int*   dst   = (const int*)d_in[6];
    float* out = (float*)d_out;

    char* w = (char*)d_ws;
    ushort* qkvp     = (ushort*)(w);
    ushort* attnb    = (ushort*)(w + 76800000);
    ushort* Wqb      = (ushort*)(w + 102400000);
    ushort* Wob      = (ushort*)(w + 102498304);
    float*  bqp      = (float*)(w + 102531072);
    int*    counts   = (int*)(w + 102532608);
    int*    fillc    = (int*)(w + 102932608);
    int*    row_start= (int*)(w + 103332608);
    int*    bsums    = (int*)(w + 103732624);
    int*    boffs    = (int*)(w + 103733136);
    int*    csr_src  = (int*)(w + 103733648);

    hipMemsetAsync(counts, 0, 800000, stream);   // counts + fillc together

    // weights prep + dst histogram in one launch (independent work)
    prep_and_count<<<6762, 128, 0, stream>>>(W_qkv, b_qkv, W_out, dst,
                                             Wqb, bqp, Wob, counts);

    // QKV projection: col-block fast -> A row-tile HBM-fetched once
    gemm_mfma<1, 1><<<dim3(3, 782), 256, 0, stream>>>(
        (const void*)x, Wqb, bqp, (void*)qkvp, N_NODES, 384);

    scan1<<<NB1, 1024, 0, stream>>>(counts, row_start, bsums);
    scan2<<<1, 128, 0, stream>>>(bsums, boffs);
    scan3<<<391, 256, 0, stream>>>(row_start, boffs);
    fill_csr<<<3125, 256, 0, stream>>>(src, dst, row_start, fillc, csr_src);

    fused_attn<<<25000, 256, 0, stream>>>(qkvp, row_start, csr_src, attnb);

    gemm_mfma<0, 0><<<dim3(1, 782), 256, 0, stream>>>(
        (const void*)attnb, Wob, b_out, (void*)out, N_NODES, 128);
}